// Round 1
// baseline (258.900 us; speedup 1.0000x reference)
//
#include <hip/hip_runtime.h>
#include <hip/hip_bf16.h>
#include <stdint.h>

#define VOCAB 50257
#define WD 300
#define KP1 320              // word dim padded to mult of 32
#define MP 50432             // vocab rows padded: 394*128

using bf16 = __hip_bfloat16;
typedef __attribute__((ext_vector_type(4))) float f32x4;
typedef __attribute__((ext_vector_type(8))) short bf16x8;

// async global->LDS, 16B per lane; LDS dest = wave-uniform base + lane*16
__device__ __forceinline__ void async_load16(const void* g, void* l) {
    __builtin_amdgcn_global_load_lds(
        (const __attribute__((address_space(1))) uint32_t*)(uintptr_t)g,
        (__attribute__((address_space(3))) uint32_t*)l, 16, 0, 0);
}

// ---------- prep: w1t = W1^T bf16 [256x320]; w2t = W2^T bf16 [256x512];
//                  w2b = W2 cast bf16 [512x256]; b4 = b2@(A+B)+b2; zbuf zeros
__global__ void prep_w(const float* __restrict__ W1, const float* __restrict__ W2,
                       const float* __restrict__ b2,
                       bf16* __restrict__ w1t, bf16* __restrict__ w2t,
                       bf16* __restrict__ w2b, float* __restrict__ b4,
                       float* __restrict__ zbuf) {
    if (blockIdx.x == 1344) {           // bias block: b4 = b2@(A+B) + b2
        __shared__ float b2s[256];
        int n = threadIdx.x;
        b2s[n] = b2[n];
        zbuf[n] = 0.0f;
        __syncthreads();
        float acc = b2s[n];
        #pragma unroll 8
        for (int k = 0; k < 256; ++k)
            acc += b2s[k] * (W2[k * 256 + n] + W2[(k + 256) * 256 + n]);
        b4[n] = acc;
        return;
    }
    int idx = blockIdx.x * 256 + threadIdx.x;
    if (idx < 256 * KP1) {                              // w1t = W1^T (zero-pad)
        int n = idx / KP1;
        int k = idx - n * KP1;
        w1t[idx] = __float2bfloat16(k < WD ? W1[k * 256 + n] : 0.0f);
    } else if (idx < 256 * KP1 + 131072) {              // w2t = W2^T
        int j = idx - 256 * KP1;
        int n = j >> 9, k = j & 511;
        w2t[j] = __float2bfloat16(W2[k * 256 + n]);
    } else {                                            // w2b = cast(W2)
        int j = idx - 256 * KP1 - 131072;
        w2b[j] = __float2bfloat16(W2[j]);
    }
}

// ---------- unified 128-row x 256-col tile (8 waves: 2 rg x 4 cgr) -----------
// AMODE 0: A bf16, row stride As elems; 3-stage PIPE (verified R8/R10/R12)
// AMODE 1: A row r = concat4(proj[ids4[m0+r]]), K = 1024; 3-stage PIPE
// AMODE 2: A fp32 rows stride WD (emb, clamped); 2-stage PIPE w/ raw barriers
template <int AMODE, bool OUT_F32>
__device__ __forceinline__ void tile_gemm(
    char* smem, const void* Av, const int* ids,
    const bf16* BT, int Bstr, const float* bias,
    void* C, int Cs, int coff, int K, int As, int m0,
    const float* zbuf)
{
    constexpr int ASZ = (AMODE == 2) ? 16384 : 8192;
    constexpr int BSZ = 16384, STAGE = ASZ + BSZ;

    const int t = threadIdx.x, w = t >> 6, lane = t & 63;
    const int rg = w >> 2, cgr = w & 3, mi = lane & 15, q = lane >> 4;
    const bf16* Ab = (const bf16*)Av;

    int4 idq = {0, 0, 0, 0};
    if constexpr (AMODE == 1) idq = ((const int4*)ids)[m0 + (t >> 2)];

    auto stage = [&](int ke, int buf) {
        char* Asm = smem + buf * STAGE;
        char* Bsm = Asm + ASZ;
        if constexpr (AMODE == 2) {
            const float* A32 = (const float*)Av;
            #pragma unroll
            for (int i = 0; i < 2; ++i) {
                int s = i * 512 + t;
                int row = s >> 3;
                int kcd = (s & 7) ^ (row & 7);
                int k = ke + kcd * 4;
                int grow = m0 + row; if (grow >= VOCAB) grow = VOCAB - 1;
                const float* g = (k <= 296) ? (A32 + (size_t)grow * WD + k) : zbuf;
                async_load16(g, Asm + i * 8192 + w * 1024);
            }
        } else {
            int row = t >> 2;
            int kcd = (t & 3) ^ ((row >> 2) & 3);
            const bf16* g;
            if constexpr (AMODE == 1) {
                int sel = ke >> 8;
                int id = (sel & 2) ? ((sel & 1) ? idq.w : idq.z)
                                   : ((sel & 1) ? idq.y : idq.x);
                g = Ab + (size_t)id * 256 + (ke & 255) + kcd * 8;
            } else {
                g = Ab + (size_t)(m0 + row) * As + ke + kcd * 8;
            }
            async_load16(g, Asm + w * 1024);
        }
        #pragma unroll
        for (int i = 0; i < 2; ++i) {
            int s = i * 512 + t;
            int col = s >> 2;
            int kcd = (s & 3) ^ ((col >> 2) & 3);
            async_load16(BT + (size_t)col * Bstr + ke + kcd * 8,
                         Bsm + i * 8192 + w * 1024);
        }
    };

    f32x4 acc[4][4] = {};

    auto compute = [&](int buf) {
        const char* Asm = smem + buf * STAGE;
        const bf16* Bs16 = (const bf16*)(Asm + ASZ);
        bf16x8 af[4], bfr[4];
        if constexpr (AMODE == 2) {
            const float* As32 = (const float*)Asm;
            #pragma unroll
            for (int r = 0; r < 4; ++r) {
                int row = rg * 64 + r * 16 + mi;
                int sl = row * 8 + ((2 * q) ^ (row & 7));
                f32x4 lo = *(const f32x4*)(As32 + sl * 4);
                f32x4 hi = *(const f32x4*)(As32 + (sl ^ 1) * 4);
                union { bf16x8 v; bf16 hh[8]; } u;
                #pragma unroll
                for (int j = 0; j < 4; ++j) u.hh[j] = __float2bfloat16(lo[j]);
                #pragma unroll
                for (int j = 0; j < 4; ++j) u.hh[4 + j] = __float2bfloat16(hi[j]);
                af[r] = u.v;
            }
        } else {
            const bf16* As16 = (const bf16*)Asm;
            #pragma unroll
            for (int r = 0; r < 4; ++r) {
                int row = rg * 64 + r * 16 + mi;
                int slot = row * 4 + (q ^ ((row >> 2) & 3));
                af[r] = *(const bf16x8*)(As16 + slot * 8);
            }
        }
        #pragma unroll
        for (int c = 0; c < 4; ++c) {
            int col = cgr * 64 + c * 16 + mi;
            int slot = col * 4 + (q ^ ((col >> 2) & 3));
            bfr[c] = *(const bf16x8*)(Bs16 + slot * 8);
        }
        #pragma unroll
        for (int r = 0; r < 4; ++r)
            #pragma unroll
            for (int c = 0; c < 4; ++c)
                acc[r][c] = __builtin_amdgcn_mfma_f32_16x16x32_bf16(af[r], bfr[c], acc[r][c], 0, 0, 0);
    };

    const int S = K >> 5;
    if constexpr (AMODE == 2) {
        // 2-stage PIPE with raw barriers (no compiler vmcnt(0) drain)
        stage(0, 0);
        for (int k0 = 0; k0 < S; ++k0) {
            if (k0 + 1 < S) {
                stage((k0 + 1) * 32, (k0 + 1) & 1);
                asm volatile("s_waitcnt vmcnt(4)\n\ts_barrier" ::: "memory");
            } else {
                asm volatile("s_waitcnt vmcnt(0)\n\ts_barrier" ::: "memory");
            }
            compute(k0 & 1);
            asm volatile("s_waitcnt lgkmcnt(0)\n\ts_barrier" ::: "memory");
        }
    } else {
        stage(0, 0);
        if (S > 1) stage(32, 1);
        for (int k0 = 0; k0 < S; ++k0) {
            if (k0 + 1 < S)
                asm volatile("s_waitcnt vmcnt(3)\n\ts_barrier" ::: "memory");
            else
                asm volatile("s_waitcnt vmcnt(0)\n\ts_barrier" ::: "memory");
            if (k0 + 2 < S) stage((k0 + 2) * 32, (k0 + 2) % 3);
            compute(k0 % 3);
        }
    }

    // epilogue: C/D layout col = lane&15, row = (lane>>4)*4 + i
    #pragma unroll
    for (int r = 0; r < 4; ++r) {
        int rowb = m0 + rg * 64 + r * 16 + q * 4;
        #pragma unroll
        for (int c = 0; c < 4; ++c) {
            int col = cgr * 64 + c * 16 + mi;
            float bv = bias[col];
            #pragma unroll
            for (int i = 0; i < 4; ++i) {
                float v = acc[r][c][i] + bv;
                size_t o = (size_t)(rowb + i) * Cs + coff + col;
                if (OUT_F32) ((float*)C)[o] = v;
                else         ((bf16*)C)[o] = __float2bfloat16(v);
            }
        }
    }
}

// ---------- D2: W4T (blocks 0..7) || proj (blocks 8..401) --------------------
__global__ __launch_bounds__(512)
void combo(const float* __restrict__ emb, const bf16* __restrict__ w1t,
           const float* __restrict__ b1, const bf16* __restrict__ w2t,
           const bf16* __restrict__ w2b, bf16* __restrict__ w4t,
           bf16* __restrict__ proj, const float* __restrict__ zbuf) {
    __shared__ char smem[73728];
    int blk = blockIdx.x;
    if (blk < 8) {
        int j = blk >> 1, s = blk & 1;
        tile_gemm<0, false>(smem, w2t + 256 * (j >> 1), nullptr,
                            w2b + 65536 * (j & 1), 256, zbuf,
                            w4t, 1024, 256 * j, 256, 512, s * 128, nullptr);
    } else {
        tile_gemm<2, false>(smem, emb, nullptr, w1t, KP1, b1,
                            proj, 256, 0, KP1, WD, (blk - 8) * 128, zbuf);
    }
}

// ---------- D3: main — h = concat4(proj[ids4]) @ W4 + b4 ---------------------
__global__ __launch_bounds__(512)
void mainK(const bf16* __restrict__ proj, const int* __restrict__ ids,
           const bf16* __restrict__ w4t, const float* __restrict__ b4,
           bf16* __restrict__ h) {
    __shared__ char smem[73728];
    tile_gemm<1, false>(smem, proj, ids, w4t, 1024, b4,
                        h, 256, 0, 1024, 256, blockIdx.x * 128, nullptr);
}

// ---------- D4..D7: tailK — one tree level-pair, split-K across blocks -------
// out[m][n] = sum_k A[m][k]*W4[k][n] + b4[n], A[m] = 1024 contiguous elems
// (concat4 of 4 consecutive 256-wide child rows). grid = RT rowtiles * KS
// K-slices; each block computes a 128x256 tile over K-slice SL and
// unsafeAtomicAdd's fp32 partials into 'out' (pre-zeroed). ks==0 adds bias.
// 2-stage raw-barrier pipe (treeK-verified pattern), 64 k per round.
template <bool INF32>
__global__ __launch_bounds__(512)
void tailK(const void* __restrict__ inv, const bf16* __restrict__ BT,
           const float* __restrict__ bias, float* __restrict__ out,
           int RT, int SL) {
    constexpr int ABYTES = INF32 ? 32768 : 16384;   // A: 128 rows x 64 k
    constexpr int STAGE = ABYTES + 32768;           // B: 256 cols x 64 k (2 subs)
    __shared__ char smem[2 * STAGE];                // 128 KB (f32) / 96 KB (bf16)

    const int t = threadIdx.x, w = t >> 6, lane = t & 63;
    const int rg = w >> 2, cgr = w & 3, mi = lane & 15, q = lane >> 4;
    const int rt = blockIdx.x % RT, ks = blockIdx.x / RT;
    const int m0 = rt * 128;
    const int k0 = ks * SL;
    const int R = SL >> 6;

    auto stage = [&](int r, int buf) {
        char* As = smem + buf * STAGE;
        char* Bs = As + ABYTES;
        const int kb = k0 + r * 64;
        if constexpr (INF32) {
            // A fp32: 16 granules(16B)/row, granule g stored at g^(row&15)
            const float* A32 = (const float*)inv;
            #pragma unroll
            for (int i = 0; i < 4; ++i) {
                int s = i * 512 + t;
                int row = s >> 4, g = s & 15;
                async_load16(A32 + (size_t)(m0 + row) * 1024 + kb + ((g ^ (row & 15)) << 2),
                             As + i * 8192 + w * 1024);
            }
        } else {
            // A bf16: 8 chunks(8 elem)/row, chunk c stored at c^(row&7)
            const bf16* A16 = (const bf16*)inv;
            #pragma unroll
            for (int i = 0; i < 2; ++i) {
                int s = i * 512 + t;
                int row = s >> 3, c = s & 7;
                async_load16(A16 + (size_t)(m0 + row) * 1024 + kb + ((c ^ (row & 7)) << 3),
                             As + i * 8192 + w * 1024);
            }
        }
        // B: verbatim treeK stageF layout (2 subs x 16 KB)
        #pragma unroll
        for (int sub = 0; sub < 2; ++sub)
            #pragma unroll
            for (int i = 0; i < 2; ++i) {
                int s = i * 512 + t;
                int col = s >> 2;
                int kcd = (s & 3) ^ ((col >> 2) & 3);
                async_load16(BT + (size_t)col * 1024 + kb + sub * 32 + kcd * 8,
                             Bs + sub * 16384 + i * 8192 + w * 1024);
            }
    };

    f32x4 acc[4][4] = {};

    auto compute = [&](int buf) {
        const char* As = smem + buf * STAGE;
        const bf16* Bs16 = (const bf16*)(As + ABYTES);
        #pragma unroll
        for (int kk = 0; kk < 2; ++kk) {
            bf16x8 af[4], bfr[4];
            #pragma unroll
            for (int r = 0; r < 4; ++r) {
                int row = rg * 64 + r * 16 + mi;
                if constexpr (INF32) {
                    const float* A32 = (const float*)As;
                    int g0 = kk * 8 + q * 2;
                    f32x4 lo = *(const f32x4*)(A32 + (row * 16 + (g0 ^ (row & 15))) * 4);
                    f32x4 hi = *(const f32x4*)(A32 + (row * 16 + ((g0 + 1) ^ (row & 15))) * 4);
                    union { bf16x8 v; bf16 hh[8]; } u;
                    #pragma unroll
                    for (int j = 0; j < 4; ++j) u.hh[j] = __float2bfloat16(lo[j]);
                    #pragma unroll
                    for (int j = 0; j < 4; ++j) u.hh[4 + j] = __float2bfloat16(hi[j]);
                    af[r] = u.v;
                } else {
                    const bf16* A16 = (const bf16*)As;
                    int c = kk * 4 + q;
                    af[r] = *(const bf16x8*)(A16 + (row * 8 + (c ^ (row & 7))) * 8);
                }
            }
            #pragma unroll
            for (int c4 = 0; c4 < 4; ++c4) {
                int col = cgr * 64 + c4 * 16 + mi;
                int slot = col * 4 + (q ^ ((col >> 2) & 3));
                bfr[c4] = *(const bf16x8*)(Bs16 + kk * 8192 + slot * 8);
            }
            #pragma unroll
            for (int r = 0; r < 4; ++r)
                #pragma unroll
                for (int c4 = 0; c4 < 4; ++c4)
                    acc[r][c4] = __builtin_amdgcn_mfma_f32_16x16x32_bf16(af[r], bfr[c4], acc[r][c4], 0, 0, 0);
        }
    };

    stage(0, 0);
    for (int r = 0; r < R; ++r) {
        if (r + 1 < R) {
            stage(r + 1, (r + 1) & 1);
            if constexpr (INF32)
                asm volatile("s_waitcnt vmcnt(8)\n\ts_barrier" ::: "memory");
            else
                asm volatile("s_waitcnt vmcnt(6)\n\ts_barrier" ::: "memory");
        } else {
            asm volatile("s_waitcnt vmcnt(0)\n\ts_barrier" ::: "memory");
        }
        compute(r & 1);
        asm volatile("s_waitcnt lgkmcnt(0)\n\ts_barrier" ::: "memory");
    }

    // epilogue: fp32 atomic accumulate; only the ks==0 slice adds bias
    #pragma unroll
    for (int r = 0; r < 4; ++r) {
        int rowb = m0 + rg * 64 + r * 16 + q * 4;
        #pragma unroll
        for (int c4 = 0; c4 < 4; ++c4) {
            int col = cgr * 64 + c4 * 16 + mi;
            float bv = (ks == 0) ? bias[col] : 0.0f;
            #pragma unroll
            for (int i = 0; i < 4; ++i)
                unsafeAtomicAdd(out + (size_t)(rowb + i) * 256 + col, acc[r][c4][i] + bv);
        }
    }
}

extern "C" void kernel_launch(void* const* d_in, const int* in_sizes, int n_in,
                              void* d_out, int out_size, void* d_ws, size_t ws_size,
                              hipStream_t stream) {
    const int*   ids = (const int*)d_in[0];
    const float* emb = (const float*)d_in[1];
    const float* W1  = (const float*)d_in[2];
    const float* b1  = (const float*)d_in[3];
    const float* W2  = (const float*)d_in[4];
    const float* b2  = (const float*)d_in[5];
    (void)in_sizes; (void)n_in; (void)out_size; (void)ws_size;

    char* ws = (char*)d_ws;
    size_t off = 0;
    float* zbuf = (float*)(ws + off); off += 1024;
    float* b4   = (float*)(ws + off); off += 1024;
    bf16* w1t = (bf16*)(ws + off); off += (size_t)256 * KP1 * 2;     // 160 KB
    bf16* w2t = (bf16*)(ws + off); off += (size_t)256 * 512 * 2;     // 256 KB
    bf16* w2b = (bf16*)(ws + off); off += (size_t)512 * 256 * 2;     // 256 KB
    bf16* w4t = (bf16*)(ws + off); off += (size_t)256 * 1024 * 2;    // 512 KB
    bf16* proj = (bf16*)(ws + off); off += (size_t)MP * 256 * 2;     // 25.8 MB
    bf16* h  = (bf16*)(ws + off); off += (size_t)65536 * 256 * 2;    // 33.5 MB
    (void)off;

    // fp32 tail partials alias proj (dead after mainK): 21504*256*4 = 22.0 MB
    float* t1f = (float*)proj;                 // [16384][256] levels 3-4
    float* t2f = t1f + (size_t)16384 * 256;    // [ 4096][256] levels 5-6
    float* t3f = t2f + (size_t)4096 * 256;     // [ 1024][256] levels 7-8

    // D1: weight casts/transposes + b4 + zeros
    prep_w<<<1345, 256, 0, stream>>>(W1, W2, b2, w1t, w2t, w2b, b4, zbuf);

    // D2: W4T (blocks 0..7) || proj (blocks 8..401, 2-stage PIPE raw barriers)
    combo<<<402, 512, 0, stream>>>(emb, w1t, b1, w2t, w2b, w4t, proj, zbuf);

    // D3: main — leaves + levels 0-1 fused (PIPE)
    mainK<<<512, 512, 0, stream>>>(proj, ids, w4t, b4, h);

    // zero tail accumulators (proj is dead now) + output
    hipMemsetAsync(t1f, 0, (size_t)(16384 + 4096 + 1024) * 256 * sizeof(float), stream);
    hipMemsetAsync(d_out, 0, (size_t)256 * 256 * sizeof(float), stream);

    // D4..D7: tree tail as split-K GEMM chain (atomic fp32 accumulate)
    tailK<false><<<256, 512, 0, stream>>>(h,   w4t, b4, t1f, 128, 512); // 16384 rows, KS=2, 8 rnds
    tailK<true ><<<128, 512, 0, stream>>>(t1f, w4t, b4, t2f,  32, 256); //  4096 rows, KS=4, 4 rnds
    tailK<true ><<< 64, 512, 0, stream>>>(t2f, w4t, b4, t3f,   8, 128); //  1024 rows, KS=8, 2 rnds
    tailK<true ><<< 16, 512, 0, stream>>>(t3f, w4t, b4, (float*)d_out, 2, 128); // roots
}

// Round 2
// 231.728 us; speedup vs baseline: 1.1173x; 1.1173x over previous
//
#include <hip/hip_runtime.h>
#include <hip/hip_bf16.h>
#include <stdint.h>

#define VOCAB 50257
#define WD 300
#define KP1 320              // word dim padded to mult of 32
#define MP 50432             // vocab rows padded: 394*128

using bf16 = __hip_bfloat16;
typedef __attribute__((ext_vector_type(4))) float f32x4;
typedef __attribute__((ext_vector_type(8))) short bf16x8;

// async global->LDS, 16B per lane; LDS dest = wave-uniform base + lane*16
__device__ __forceinline__ void async_load16(const void* g, void* l) {
    __builtin_amdgcn_global_load_lds(
        (const __attribute__((address_space(1))) uint32_t*)(uintptr_t)g,
        (__attribute__((address_space(3))) uint32_t*)l, 16, 0, 0);
}

// ---------- prep: w1t = W1^T bf16 [256x320]; w2t = W2^T bf16 [256x512];
//                  w2b = W2 cast bf16 [512x256]; b4 = b2@(A+B)+b2; zbuf zeros
__global__ void prep_w(const float* __restrict__ W1, const float* __restrict__ W2,
                       const float* __restrict__ b2,
                       bf16* __restrict__ w1t, bf16* __restrict__ w2t,
                       bf16* __restrict__ w2b, float* __restrict__ b4,
                       float* __restrict__ zbuf) {
    if (blockIdx.x == 1344) {           // bias block: b4 = b2@(A+B) + b2
        __shared__ float b2s[256];
        int n = threadIdx.x;
        b2s[n] = b2[n];
        zbuf[n] = 0.0f;
        __syncthreads();
        float acc = b2s[n];
        #pragma unroll 8
        for (int k = 0; k < 256; ++k)
            acc += b2s[k] * (W2[k * 256 + n] + W2[(k + 256) * 256 + n]);
        b4[n] = acc;
        return;
    }
    int idx = blockIdx.x * 256 + threadIdx.x;
    if (idx < 256 * KP1) {                              // w1t = W1^T (zero-pad)
        int n = idx / KP1;
        int k = idx - n * KP1;
        w1t[idx] = __float2bfloat16(k < WD ? W1[k * 256 + n] : 0.0f);
    } else if (idx < 256 * KP1 + 131072) {              // w2t = W2^T
        int j = idx - 256 * KP1;
        int n = j >> 9, k = j & 511;
        w2t[j] = __float2bfloat16(W2[k * 256 + n]);
    } else {                                            // w2b = cast(W2)
        int j = idx - 256 * KP1 - 131072;
        w2b[j] = __float2bfloat16(W2[j]);
    }
}

// ---------- unified 128-row x 256-col tile (8 waves: 2 rg x 4 cgr) -----------
// AMODE 0: A bf16, row stride As elems; 3-stage PIPE (verified R8/R10/R12)
// AMODE 1: A row r = concat4(proj[ids4[m0+r]]), K = 1024; 3-stage PIPE
// AMODE 2: A fp32 rows stride WD (emb, clamped); 2-stage PIPE w/ raw barriers
template <int AMODE, bool OUT_F32>
__device__ __forceinline__ void tile_gemm(
    char* smem, const void* Av, const int* ids,
    const bf16* BT, int Bstr, const float* bias,
    void* C, int Cs, int coff, int K, int As, int m0,
    const float* zbuf)
{
    constexpr int ASZ = (AMODE == 2) ? 16384 : 8192;
    constexpr int BSZ = 16384, STAGE = ASZ + BSZ;

    const int t = threadIdx.x, w = t >> 6, lane = t & 63;
    const int rg = w >> 2, cgr = w & 3, mi = lane & 15, q = lane >> 4;
    const bf16* Ab = (const bf16*)Av;

    int4 idq = {0, 0, 0, 0};
    if constexpr (AMODE == 1) idq = ((const int4*)ids)[m0 + (t >> 2)];

    auto stage = [&](int ke, int buf) {
        char* Asm = smem + buf * STAGE;
        char* Bsm = Asm + ASZ;
        if constexpr (AMODE == 2) {
            const float* A32 = (const float*)Av;
            #pragma unroll
            for (int i = 0; i < 2; ++i) {
                int s = i * 512 + t;
                int row = s >> 3;
                int kcd = (s & 7) ^ (row & 7);
                int k = ke + kcd * 4;
                int grow = m0 + row; if (grow >= VOCAB) grow = VOCAB - 1;
                const float* g = (k <= 296) ? (A32 + (size_t)grow * WD + k) : zbuf;
                async_load16(g, Asm + i * 8192 + w * 1024);
            }
        } else {
            int row = t >> 2;
            int kcd = (t & 3) ^ ((row >> 2) & 3);
            const bf16* g;
            if constexpr (AMODE == 1) {
                int sel = ke >> 8;
                int id = (sel & 2) ? ((sel & 1) ? idq.w : idq.z)
                                   : ((sel & 1) ? idq.y : idq.x);
                g = Ab + (size_t)id * 256 + (ke & 255) + kcd * 8;
            } else {
                g = Ab + (size_t)(m0 + row) * As + ke + kcd * 8;
            }
            async_load16(g, Asm + w * 1024);
        }
        #pragma unroll
        for (int i = 0; i < 2; ++i) {
            int s = i * 512 + t;
            int col = s >> 2;
            int kcd = (s & 3) ^ ((col >> 2) & 3);
            async_load16(BT + (size_t)col * Bstr + ke + kcd * 8,
                         Bsm + i * 8192 + w * 1024);
        }
    };

    f32x4 acc[4][4] = {};

    auto compute = [&](int buf) {
        const char* Asm = smem + buf * STAGE;
        const bf16* Bs16 = (const bf16*)(Asm + ASZ);
        bf16x8 af[4], bfr[4];
        if constexpr (AMODE == 2) {
            const float* As32 = (const float*)Asm;
            #pragma unroll
            for (int r = 0; r < 4; ++r) {
                int row = rg * 64 + r * 16 + mi;
                int sl = row * 8 + ((2 * q) ^ (row & 7));
                f32x4 lo = *(const f32x4*)(As32 + sl * 4);
                f32x4 hi = *(const f32x4*)(As32 + (sl ^ 1) * 4);
                union { bf16x8 v; bf16 hh[8]; } u;
                #pragma unroll
                for (int j = 0; j < 4; ++j) u.hh[j] = __float2bfloat16(lo[j]);
                #pragma unroll
                for (int j = 0; j < 4; ++j) u.hh[4 + j] = __float2bfloat16(hi[j]);
                af[r] = u.v;
            }
        } else {
            const bf16* As16 = (const bf16*)Asm;
            #pragma unroll
            for (int r = 0; r < 4; ++r) {
                int row = rg * 64 + r * 16 + mi;
                int slot = row * 4 + (q ^ ((row >> 2) & 3));
                af[r] = *(const bf16x8*)(As16 + slot * 8);
            }
        }
        #pragma unroll
        for (int c = 0; c < 4; ++c) {
            int col = cgr * 64 + c * 16 + mi;
            int slot = col * 4 + (q ^ ((col >> 2) & 3));
            bfr[c] = *(const bf16x8*)(Bs16 + slot * 8);
        }
        #pragma unroll
        for (int r = 0; r < 4; ++r)
            #pragma unroll
            for (int c = 0; c < 4; ++c)
                acc[r][c] = __builtin_amdgcn_mfma_f32_16x16x32_bf16(af[r], bfr[c], acc[r][c], 0, 0, 0);
    };

    const int S = K >> 5;
    if constexpr (AMODE == 2) {
        // 2-stage PIPE with raw barriers (no compiler vmcnt(0) drain)
        stage(0, 0);
        for (int k0 = 0; k0 < S; ++k0) {
            if (k0 + 1 < S) {
                stage((k0 + 1) * 32, (k0 + 1) & 1);
                asm volatile("s_waitcnt vmcnt(4)\n\ts_barrier" ::: "memory");
            } else {
                asm volatile("s_waitcnt vmcnt(0)\n\ts_barrier" ::: "memory");
            }
            compute(k0 & 1);
            asm volatile("s_waitcnt lgkmcnt(0)\n\ts_barrier" ::: "memory");
        }
    } else {
        stage(0, 0);
        if (S > 1) stage(32, 1);
        for (int k0 = 0; k0 < S; ++k0) {
            if (k0 + 1 < S)
                asm volatile("s_waitcnt vmcnt(3)\n\ts_barrier" ::: "memory");
            else
                asm volatile("s_waitcnt vmcnt(0)\n\ts_barrier" ::: "memory");
            if (k0 + 2 < S) stage((k0 + 2) * 32, (k0 + 2) % 3);
            compute(k0 % 3);
        }
    }

    // epilogue: C/D layout col = lane&15, row = (lane>>4)*4 + i
    #pragma unroll
    for (int r = 0; r < 4; ++r) {
        int rowb = m0 + rg * 64 + r * 16 + q * 4;
        #pragma unroll
        for (int c = 0; c < 4; ++c) {
            int col = cgr * 64 + c * 16 + mi;
            float bv = bias[col];
            #pragma unroll
            for (int i = 0; i < 4; ++i) {
                float v = acc[r][c][i] + bv;
                size_t o = (size_t)(rowb + i) * Cs + coff + col;
                if (OUT_F32) ((float*)C)[o] = v;
                else         ((bf16*)C)[o] = __float2bfloat16(v);
            }
        }
    }
}

// ---------- D2: W4T (blocks 0..7) || proj (blocks 8..401) --------------------
__global__ __launch_bounds__(512)
void combo(const float* __restrict__ emb, const bf16* __restrict__ w1t,
           const float* __restrict__ b1, const bf16* __restrict__ w2t,
           const bf16* __restrict__ w2b, bf16* __restrict__ w4t,
           bf16* __restrict__ proj, const float* __restrict__ zbuf) {
    __shared__ char smem[73728];
    int blk = blockIdx.x;
    if (blk < 8) {
        int j = blk >> 1, s = blk & 1;
        tile_gemm<0, false>(smem, w2t + 256 * (j >> 1), nullptr,
                            w2b + 65536 * (j & 1), 256, zbuf,
                            w4t, 1024, 256 * j, 256, 512, s * 128, nullptr);
    } else {
        tile_gemm<2, false>(smem, emb, nullptr, w1t, KP1, b1,
                            proj, 256, 0, KP1, WD, (blk - 8) * 128, zbuf);
    }
}

// ---------- D3: main — h = concat4(proj[ids4]) @ W4 + b4 ---------------------
__global__ __launch_bounds__(512)
void mainK(const bf16* __restrict__ proj, const int* __restrict__ ids,
           const bf16* __restrict__ w4t, const float* __restrict__ b4,
           bf16* __restrict__ h) {
    __shared__ char smem[73728];
    tile_gemm<1, false>(smem, proj, ids, w4t, 1024, b4,
                        h, 256, 0, 1024, 256, blockIdx.x * 128, nullptr);
}

// ---------- D4..D7: tailC — one tree level-pair, col-split (NO atomics) ------
// out[m][n] = sum_k A[m][k]*W4[k][n] + b4[n], A[m] = 1024 contiguous bf16
// (concat4 of 4 consecutive 256-wide child rows). grid = RT rowtiles x 4
// colgroups; block computes a COMPLETE 128x64 output tile over full K=1024.
// B slice (64 cols x 1024 k = 128 KB) staged in LDS ONCE; A double-buffered
// 2 x 8 KB, 32 rounds x 32 k. Plain stores. LDS = 144 KB -> 1 block/CU.
// Waves: 2 rg x 4 cgr; wave tile = 64 rows x 16 cols (acc[4] frags).
template <bool OUT_F32>
__global__ __launch_bounds__(512)
void tailC(const bf16* __restrict__ in, const bf16* __restrict__ BT,
           const float* __restrict__ bias, void* __restrict__ out, int RT) {
    __shared__ char smem[147456];          // B 131072 + A 2*8192
    char* Bs  = smem;
    char* As0 = smem + 131072;

    const int t = threadIdx.x, w = t >> 6, lane = t & 63;
    const int rg = w >> 2, cgr = w & 3, mi = lane & 15, q = lane >> 4;
    const int rt = blockIdx.x >> 2, cg = blockIdx.x & 3;
    const int m0 = rt * 128;
    const int c0 = cg * 64;

    // ---- B stage: whole 64-col x 1024-k slice, once (16 loads/thread) ----
    // LDS layout: byte = kc*4096 + col*64 + slot*16, slot = g ^ ((col>>2)&3)
    #pragma unroll
    for (int i = 0; i < 16; ++i) {
        int s = i * 512 + t;
        int kc = s >> 8;               // 0..31  (32-k chunk)
        int col = (s >> 2) & 63;
        int slot = s & 3;
        int g = slot ^ ((col >> 2) & 3);
        async_load16(BT + (size_t)(c0 + col) * 1024 + kc * 32 + g * 8,
                     Bs + i * 8192 + w * 1024);
    }

    // A stage: 128 rows x 32 k = 8 KB (1 load/thread)
    // LDS layout: byte = row*64 + slot*16, slot = g ^ ((row>>1)&3)
    auto stageA = [&](int r, int buf) {
        int row = t >> 2, slot = t & 3;
        int g = slot ^ ((row >> 1) & 3);
        async_load16(in + (size_t)(m0 + row) * 1024 + r * 32 + g * 8,
                     As0 + buf * 8192 + w * 1024);
    };

    f32x4 acc[4] = {};

    auto computeR = [&](int r, int buf) {
        const bf16* As16 = (const bf16*)(As0 + buf * 8192);
        const bf16* Bc   = (const bf16*)(Bs + r * 4096);
        bf16x8 bfr;
        {
            int col = cgr * 16 + mi;
            int slot = q ^ ((col >> 2) & 3);
            bfr = *(const bf16x8*)(Bc + col * 32 + slot * 8);
        }
        #pragma unroll
        for (int ri = 0; ri < 4; ++ri) {
            int row = rg * 64 + ri * 16 + mi;
            int slot = q ^ ((row >> 1) & 3);
            bf16x8 af = *(const bf16x8*)(As16 + row * 32 + slot * 8);
            acc[ri] = __builtin_amdgcn_mfma_f32_16x16x32_bf16(af, bfr, acc[ri], 0, 0, 0);
        }
    };

    stageA(0, 0);
    for (int r = 0; r < 32; ++r) {
        if (r + 1 < 32) {
            stageA(r + 1, (r + 1) & 1);
            asm volatile("s_waitcnt vmcnt(1)\n\ts_barrier" ::: "memory");
        } else {
            asm volatile("s_waitcnt vmcnt(0)\n\ts_barrier" ::: "memory");
        }
        computeR(r, r & 1);
        asm volatile("s_waitcnt lgkmcnt(0)\n\ts_barrier" ::: "memory");
    }

    // epilogue: plain stores; col = lane&15, row = (lane>>4)*4 + i
    const int col = c0 + cgr * 16 + mi;
    const float bv = bias[col];
    #pragma unroll
    for (int ri = 0; ri < 4; ++ri) {
        int rowb = m0 + rg * 64 + ri * 16 + q * 4;
        #pragma unroll
        for (int i = 0; i < 4; ++i) {
            float v = acc[ri][i] + bv;
            size_t o = (size_t)(rowb + i) * 256 + col;
            if (OUT_F32) ((float*)out)[o] = v;
            else         ((bf16*)out)[o] = __float2bfloat16(v);
        }
    }
}

extern "C" void kernel_launch(void* const* d_in, const int* in_sizes, int n_in,
                              void* d_out, int out_size, void* d_ws, size_t ws_size,
                              hipStream_t stream) {
    const int*   ids = (const int*)d_in[0];
    const float* emb = (const float*)d_in[1];
    const float* W1  = (const float*)d_in[2];
    const float* b1  = (const float*)d_in[3];
    const float* W2  = (const float*)d_in[4];
    const float* b2  = (const float*)d_in[5];
    (void)in_sizes; (void)n_in; (void)out_size; (void)ws_size;

    char* ws = (char*)d_ws;
    size_t off = 0;
    float* zbuf = (float*)(ws + off); off += 1024;
    float* b4   = (float*)(ws + off); off += 1024;
    bf16* w1t = (bf16*)(ws + off); off += (size_t)256 * KP1 * 2;     // 160 KB
    bf16* w2t = (bf16*)(ws + off); off += (size_t)256 * 512 * 2;     // 256 KB
    bf16* w2b = (bf16*)(ws + off); off += (size_t)512 * 256 * 2;     // 256 KB
    bf16* w4t = (bf16*)(ws + off); off += (size_t)256 * 1024 * 2;    // 512 KB
    bf16* proj = (bf16*)(ws + off); off += (size_t)MP * 256 * 2;     // 25.8 MB
    bf16* h  = (bf16*)(ws + off); off += (size_t)65536 * 256 * 2;    // 33.5 MB
    (void)off;

    // bf16 tail intermediates alias proj (dead after mainK): 11 MB total
    bf16* t1 = (bf16*)proj;                 // [16384][256] levels 3-4
    bf16* t2 = t1 + (size_t)16384 * 256;    // [ 4096][256] levels 5-6
    bf16* t3 = t2 + (size_t)4096 * 256;     // [ 1024][256] levels 7-8

    // D1: weight casts/transposes + b4 + zeros
    prep_w<<<1345, 256, 0, stream>>>(W1, W2, b2, w1t, w2t, w2b, b4, zbuf);

    // D2: W4T (blocks 0..7) || proj (blocks 8..401, 2-stage PIPE raw barriers)
    combo<<<402, 512, 0, stream>>>(emb, w1t, b1, w2t, w2b, w4t, proj, zbuf);

    // D3: main — leaves + levels 0-1 fused (PIPE)
    mainK<<<512, 512, 0, stream>>>(proj, ids, w4t, b4, h);

    // D4..D7: tree tail, col-split complete tiles (no atomics, no memsets)
    tailC<false><<<512, 512, 0, stream>>>(h,  w4t, b4, t1, 128); // 16384 rows
    tailC<false><<<128, 512, 0, stream>>>(t1, w4t, b4, t2, 32); //  4096 rows
    tailC<false><<< 32, 512, 0, stream>>>(t2, w4t, b4, t3, 8);  //  1024 rows
    tailC<true ><<<  8, 512, 0, stream>>>(t3, w4t, b4, d_out, 2); // 256 roots
}